// Round 5
// baseline (601.187 us; speedup 1.0000x reference)
//
#include <hip/hip_runtime.h>
#include <hip/hip_cooperative_groups.h>
namespace cg = cooperative_groups;

#define BATCH 8192
#define FEATS 4096
#define NBLK 1024                         // cooperative grid: 4 blocks/CU on 256 CUs
#define CHUNKS 256                        // row chunks for partial sums
#define RPC (BATCH / CHUNKS)              // 32 rows per chunk
#define SR (BATCH / NBLK)                 // 8 rows per block in scale phase
#define RBLK 64                           // reduce blocks
#define KSLICES 4
#define KPER (CHUNKS / KSLICES)           // 64 chunks per k-slice

typedef float v4f __attribute__((ext_vector_type(4)));  // native vector for nontemporal builtin

// ws layout: [0, CHUNKS*FEATS) doubles = partial column sums (8 MB)
//            then FEATS doubles = means
//            then RBLK doubles = per-block min
//            then RBLK doubles = per-block max
//            then FEATS floats  = per-feature scale

__global__ __launch_bounds__(256) void fused_kernel(const float* __restrict__ in,
                                                    const float* __restrict__ noise,
                                                    float* __restrict__ out,
                                                    double* __restrict__ partials,
                                                    double* __restrict__ means,
                                                    double* __restrict__ bmin,
                                                    double* __restrict__ bmax,
                                                    float* __restrict__ scale) {
    cg::grid_group grid = cg::this_grid();
    const int t = threadIdx.x;
    const int gid = blockIdx.x;

    __shared__ double sred[KSLICES][64];
    __shared__ unsigned s_hist[FEATS + 1];
    __shared__ double s_mm[2];

    // ---- phase 1: column partial sums (all 1024 blocks) ----
    {
        const int cgp = gid & 3;              // column group of 1024 cols
        const int ch = gid >> 2;              // row chunk 0..255
        const int colBase = cgp * 1024 + t * 4;
        const int row0 = ch * RPC;
        const float4* p = (const float4*)in + (size_t)row0 * (FEATS / 4) + (colBase >> 2);
        double a0 = 0.0, a1 = 0.0, a2 = 0.0, a3 = 0.0;
#pragma unroll
        for (int r = 0; r < RPC; ++r) {
            float4 v = p[(size_t)r * (FEATS / 4)];
            a0 += (double)v.x; a1 += (double)v.y; a2 += (double)v.z; a3 += (double)v.w;
        }
        double* dst = partials + (size_t)ch * FEATS + colBase;
        dst[0] = a0; dst[1] = a1; dst[2] = a2; dst[3] = a3;
    }
    grid.sync();

    // ---- phase 2: reduce to means + per-block min/max (blocks 0..63) ----
    if (gid < RBLK) {
        const int cL = t & 63;                // column within 64-col slab
        const int ks = t >> 6;                // k-slice (== wave id)
        const int c = gid * 64 + cL;
        double s = 0.0;
#pragma unroll 8
        for (int k = 0; k < KPER; ++k)
            s += partials[(size_t)(ks * KPER + k) * FEATS + c];
        sred[ks][cL] = s;
        __syncthreads();
        if (ks == 0) {                        // fixed-order combine -> deterministic
            double m = ((sred[0][cL] + sred[1][cL]) + sred[2][cL]) + sred[3][cL];
            m *= (1.0 / (double)BATCH);       // /8192 exact pow2 scale
            means[c] = m;
            double lmin = m, lmax = m;
#pragma unroll
            for (int off = 32; off > 0; off >>= 1) {
                lmin = fmin(lmin, __shfl_down(lmin, off));
                lmax = fmax(lmax, __shfl_down(lmax, off));
            }
            if (cL == 0) { bmin[gid] = lmin; bmax[gid] = lmax; }
        }
    }
    grid.sync();

    // ---- phase 3: config (block 0 only) ----
    if (gid == 0) {
        if (t == 0) {
            double a = bmin[0], b = bmax[0];
            for (int i = 1; i < RBLK; ++i) { a = fmin(a, bmin[i]); b = fmax(b, bmax[i]); }
            s_mm[0] = a; s_mm[1] = b;
        }
        for (int i = t; i < FEATS + 1; i += 256) s_hist[i] = 0;
        __syncthreads();
        const double xmin = s_mm[0];
        const double denom = s_mm[1] - xmin;
        int binr[16];
#pragma unroll
        for (int k = 0; k < 16; ++k) {
            int c2 = t + k * 256;
            // match numpy op order: F*(x - xmin) then divide, truncate toward zero
            double b = ((double)FEATS * (means[c2] - xmin)) / denom;
            int bi = (int)b;
            binr[k] = bi;
            atomicAdd(&s_hist[bi], 1u);
        }
        __syncthreads();
        const double K = -2.302585092994045684017991454684364208;  // ln(0.1)
#pragma unroll
        for (int k = 0; k < 16; ++k) {
            int c2 = t + k * 256;
            unsigned cnt = s_hist[binr[k]];
            double dr = (cnt == 1u) ? 0.1 : exp(K / (0.6 * (double)cnt));
            double sg = sqrt(dr / (1.0 - dr));
            scale[c2] = (float)(1.0 + sg * (double)noise[c2]);
        }
    }
    grid.sync();

    // ---- phase 4: scale & write (all 1024 blocks, 8 rows each) ----
    {
        const float4* sc4 = (const float4*)scale;
        const int row0 = gid * SR;
#pragma unroll
        for (int ccb = 0; ccb < 4; ++ccb) {
            const int col = ccb * 256 + t;            // float4-column
            const float4 s = sc4[col];                // loaded once, reused for SR rows
            const float4* pin = (const float4*)in + (size_t)row0 * (FEATS / 4) + col;
            float4* pout = (float4*)out + (size_t)row0 * (FEATS / 4) + col;
#pragma unroll
            for (int r = 0; r < SR; ++r) {
                float4 v = pin[(size_t)r * (FEATS / 4)];
                v.x *= s.x; v.y *= s.y; v.z *= s.z; v.w *= s.w;
                // nontemporal: don't evict the L3-resident input with the out-stream
                v4f nv = {v.x, v.y, v.z, v.w};
                __builtin_nontemporal_store(nv, (v4f*)&pout[(size_t)r * (FEATS / 4)]);
            }
        }
    }
}

extern "C" void kernel_launch(void* const* d_in, const int* in_sizes, int n_in,
                              void* d_out, int out_size, void* d_ws, size_t ws_size,
                              hipStream_t stream) {
    const float* in = (const float*)d_in[0];
    const float* noise = (const float*)d_in[1];
    float* out = (float*)d_out;
    double* partials = (double*)d_ws;
    double* means = partials + (size_t)CHUNKS * FEATS;
    double* bmin = means + FEATS;
    double* bmax = bmin + RBLK;
    float* scale = (float*)(bmax + RBLK);

    void* args[] = {(void*)&in, (void*)&noise, (void*)&out, (void*)&partials,
                    (void*)&means, (void*)&bmin, (void*)&bmax, (void*)&scale};
    hipLaunchCooperativeKernel((const void*)fused_kernel, dim3(NBLK), dim3(256),
                               args, 0, stream);
}

// Round 6
// 257.451 us; speedup vs baseline: 2.3352x; 2.3352x over previous
//
#include <hip/hip_runtime.h>

#define BATCH 8192
#define FEATS 4096
#define CHUNKS 128                        // row chunks for partial sums
#define ROWS_PER_CHUNK (BATCH / CHUNKS)   // 64
#define SROWS 16                          // rows per block in scale pass
#define RBLK 64                           // reduce blocks
#define KSLICES 4
#define KPER (CHUNKS / KSLICES)           // 32 chunks per k-slice

typedef float v4f __attribute__((ext_vector_type(4)));  // native vector for nontemporal builtin

// ws layout: [0, CHUNKS*FEATS) doubles = partial column sums (4 MB)
//            then FEATS doubles = means
//            then RBLK doubles = per-block min
//            then RBLK doubles = per-block max
//            then FEATS floats  = per-feature scale

__global__ __launch_bounds__(256) void colsum_part(const float* __restrict__ in,
                                                   double* __restrict__ partials) {
    // grid.x = 4 column groups of 1024 cols; grid.y = CHUNKS row chunks (512 blocks)
    const int colBase = blockIdx.x * 1024 + threadIdx.x * 4;
    const int row0 = blockIdx.y * ROWS_PER_CHUNK;
    const float4* p = (const float4*)in + (size_t)row0 * (FEATS / 4) + (colBase >> 2);
    double a0 = 0.0, a1 = 0.0, a2 = 0.0, a3 = 0.0;
#pragma unroll 16
    for (int r = 0; r < ROWS_PER_CHUNK; ++r) {
        float4 v = p[(size_t)r * (FEATS / 4)];
        a0 += (double)v.x; a1 += (double)v.y; a2 += (double)v.z; a3 += (double)v.w;
    }
    double* dst = partials + (size_t)blockIdx.y * FEATS + colBase;
    dst[0] = a0; dst[1] = a1; dst[2] = a2; dst[3] = a3;
}

// 64 blocks x 256 threads; each block reduces 64 columns (4 k-slices of 32 chunks,
// combined in fixed order -> deterministic).
__global__ __launch_bounds__(256) void reduce_mean(const double* __restrict__ partials,
                                                   double* __restrict__ means,
                                                   double* __restrict__ bmin,
                                                   double* __restrict__ bmax) {
    const int t = threadIdx.x;
    const int cLocal = t & 63;            // column within block's 64-col slab
    const int ks = t >> 6;                // k-slice 0..3 (== wave id)
    const int c = blockIdx.x * 64 + cLocal;

    double s = 0.0;
#pragma unroll 8
    for (int k = 0; k < KPER; ++k)
        s += partials[(size_t)(ks * KPER + k) * FEATS + c];

    __shared__ double sred[KSLICES][64];
    sred[ks][cLocal] = s;
    __syncthreads();

    if (ks == 0) {  // wave 0 finalizes the block's 64 columns
        double m = ((sred[0][cLocal] + sred[1][cLocal]) + sred[2][cLocal]) + sred[3][cLocal];
        m *= (1.0 / (double)BATCH);       // /8192 exact pow2 scale
        means[c] = m;
        double lmin = m, lmax = m;
#pragma unroll
        for (int off = 32; off > 0; off >>= 1) {
            lmin = fmin(lmin, __shfl_down(lmin, off));
            lmax = fmax(lmax, __shfl_down(lmax, off));
        }
        if (cLocal == 0) { bmin[blockIdx.x] = lmin; bmax[blockIdx.x] = lmax; }
    }
}

__global__ __launch_bounds__(1024) void config_kernel(const double* __restrict__ means,
                                                      const double* __restrict__ bmin,
                                                      const double* __restrict__ bmax,
                                                      const float* __restrict__ noise,
                                                      float* __restrict__ scale) {
    __shared__ unsigned s_hist[FEATS + 1];
    __shared__ double s_mm[2];
    const int tid = threadIdx.x;

    // parallel min/max over the 64 per-block entries (one wave)
    if (tid < 64) {
        double a = bmin[tid], b = bmax[tid];
#pragma unroll
        for (int off = 32; off > 0; off >>= 1) {
            a = fmin(a, __shfl_down(a, off));
            b = fmax(b, __shfl_down(b, off));
        }
        if (tid == 0) { s_mm[0] = a; s_mm[1] = b; }
    }
    for (int i = tid; i < FEATS + 1; i += 1024) s_hist[i] = 0;
    __syncthreads();

    const double xmin = s_mm[0];
    const double denom = s_mm[1] - xmin;

    int binr[4];
#pragma unroll
    for (int k = 0; k < 4; ++k) {
        int c = tid + k * 1024;
        // match numpy op order: F*(x - xmin) then divide, truncate toward zero
        double b = ((double)FEATS * (means[c] - xmin)) / denom;
        int bi = (int)b;
        binr[k] = bi;
        atomicAdd(&s_hist[bi], 1u);
    }
    __syncthreads();

    const double K = -2.302585092994045684017991454684364208;  // ln(0.1)
#pragma unroll
    for (int k = 0; k < 4; ++k) {
        int c = tid + k * 1024;
        unsigned cnt = s_hist[binr[k]];
        double dr = (cnt == 1u) ? 0.1 : exp(K / (0.6 * (double)cnt));
        double sg = sqrt(dr / (1.0 - dr));
        scale[c] = (float)(1.0 + sg * (double)noise[c]);
    }
}

__global__ __launch_bounds__(256) void scale_kernel(const float4* __restrict__ in,
                                                    const float4* __restrict__ scale,
                                                    float4* __restrict__ out) {
    // blockIdx.x & 3 -> column group (256 float4 cols), blockIdx.x >> 2 -> row group
    const int col = (blockIdx.x & 3) * 256 + threadIdx.x;  // float4-column, 0..1023
    const int row0 = (blockIdx.x >> 2) * SROWS;
    const float4 s = scale[col];  // loaded ONCE per thread, reused for SROWS rows
    const float4* pin = in + (size_t)row0 * (FEATS / 4) + col;
    float4* pout = out + (size_t)row0 * (FEATS / 4) + col;
#pragma unroll
    for (int r = 0; r < SROWS; ++r) {
        float4 v = pin[(size_t)r * (FEATS / 4)];
        v.x *= s.x; v.y *= s.y; v.z *= s.z; v.w *= s.w;
        // nontemporal: don't let the out-stream evict the L3-resident input
        v4f nv = {v.x, v.y, v.z, v.w};
        __builtin_nontemporal_store(nv, (v4f*)&pout[(size_t)r * (FEATS / 4)]);
    }
}

extern "C" void kernel_launch(void* const* d_in, const int* in_sizes, int n_in,
                              void* d_out, int out_size, void* d_ws, size_t ws_size,
                              hipStream_t stream) {
    const float* in = (const float*)d_in[0];
    const float* noise = (const float*)d_in[1];
    float* out = (float*)d_out;
    double* partials = (double*)d_ws;
    double* means = partials + (size_t)CHUNKS * FEATS;
    double* bmin = means + FEATS;
    double* bmax = bmin + RBLK;
    float* scale = (float*)(bmax + RBLK);

    dim3 g1(4, CHUNKS);
    colsum_part<<<g1, 256, 0, stream>>>(in, partials);
    reduce_mean<<<RBLK, 256, 0, stream>>>(partials, means, bmin, bmax);
    config_kernel<<<1, 1024, 0, stream>>>(means, bmin, bmax, noise, scale);
    scale_kernel<<<4 * (BATCH / SROWS), 256, 0, stream>>>(
        (const float4*)in, (const float4*)scale, (float4*)out);
}

// Round 7
// 257.375 us; speedup vs baseline: 2.3358x; 1.0003x over previous
//
#include <hip/hip_runtime.h>

#define BATCH 8192
#define FEATS 4096
#define CHUNKS 128                        // row chunks for partial sums
#define ROWS_PER_CHUNK (BATCH / CHUNKS)   // 64
#define SROWS 16                          // rows per block in scale pass
#define RBLK 64                           // reduce blocks
#define KSLICES 4
#define KPER (CHUNKS / KSLICES)           // 32 chunks per k-slice

typedef float v4f __attribute__((ext_vector_type(4)));  // native vector for nontemporal builtin

// ws layout: [0, CHUNKS*FEATS) doubles = partial column sums (4 MB)
//            then FEATS doubles = means

__global__ __launch_bounds__(256) void colsum_part(const float* __restrict__ in,
                                                   double* __restrict__ partials) {
    // grid.x = 4 column groups of 1024 cols; grid.y = CHUNKS row chunks (512 blocks)
    const int colBase = blockIdx.x * 1024 + threadIdx.x * 4;
    const int row0 = blockIdx.y * ROWS_PER_CHUNK;
    const float4* p = (const float4*)in + (size_t)row0 * (FEATS / 4) + (colBase >> 2);
    double a0 = 0.0, a1 = 0.0, a2 = 0.0, a3 = 0.0;
#pragma unroll 16
    for (int r = 0; r < ROWS_PER_CHUNK; ++r) {
        float4 v = p[(size_t)r * (FEATS / 4)];
        a0 += (double)v.x; a1 += (double)v.y; a2 += (double)v.z; a3 += (double)v.w;
    }
    double* dst = partials + (size_t)blockIdx.y * FEATS + colBase;
    dst[0] = a0; dst[1] = a1; dst[2] = a2; dst[3] = a3;
}

// 64 blocks x 256 threads; each block reduces 64 columns (4 k-slices of 32 chunks,
// combined in fixed order -> deterministic).
__global__ __launch_bounds__(256) void reduce_mean(const double* __restrict__ partials,
                                                   double* __restrict__ means) {
    const int t = threadIdx.x;
    const int cLocal = t & 63;            // column within block's 64-col slab
    const int ks = t >> 6;                // k-slice 0..3 (== wave id)
    const int c = blockIdx.x * 64 + cLocal;

    double s = 0.0;
#pragma unroll 8
    for (int k = 0; k < KPER; ++k)
        s += partials[(size_t)(ks * KPER + k) * FEATS + c];

    __shared__ double sred[KSLICES][64];
    sred[ks][cLocal] = s;
    __syncthreads();

    if (ks == 0) {  // wave 0 finalizes the block's 64 columns
        double m = ((sred[0][cLocal] + sred[1][cLocal]) + sred[2][cLocal]) + sred[3][cLocal];
        means[c] = m * (1.0 / (double)BATCH);  // /8192 exact pow2 scale
    }
}

// 2048 blocks x 256 threads. Each block redundantly recomputes the config
// (min/max + histogram over the 4096 f64 means — fixed-order f64 ops, so every
// block derives bit-identical scales), then streams its 16-row slab.
__global__ __launch_bounds__(256) void scale_fused(const float* __restrict__ in,
                                                   const double* __restrict__ means,
                                                   const float* __restrict__ noise,
                                                   float* __restrict__ out) {
    __shared__ unsigned s_hist[FEATS + 1];
    __shared__ double smin[4], smax[4];
    const int t = threadIdx.x;

    // --- pass 1: local min/max over 16 means/thread + zero hist ---
    double lmin = 1e300, lmax = -1e300;
#pragma unroll
    for (int k = 0; k < 16; ++k) {
        double m = means[t + k * 256];
        lmin = fmin(lmin, m);
        lmax = fmax(lmax, m);
    }
#pragma unroll
    for (int off = 32; off > 0; off >>= 1) {
        lmin = fmin(lmin, __shfl_down(lmin, off));
        lmax = fmax(lmax, __shfl_down(lmax, off));
    }
    if ((t & 63) == 0) { smin[t >> 6] = lmin; smax[t >> 6] = lmax; }
    for (int i = t; i < FEATS + 1; i += 256) s_hist[i] = 0;
    __syncthreads();

    // min/max are order-independent (exact), so per-thread recombination is fine
    const double xmin = fmin(fmin(smin[0], smin[1]), fmin(smin[2], smin[3]));
    const double xmax = fmax(fmax(smax[0], smax[1]), fmax(smax[2], smax[3]));
    const double denom = xmax - xmin;

    // --- pass 2: histogram of bins (means re-read; L2-hot) ---
#pragma unroll
    for (int k = 0; k < 16; ++k) {
        // match numpy op order: F*(x - xmin) then divide, truncate toward zero
        double b = ((double)FEATS * (means[t + k * 256] - xmin)) / denom;
        atomicAdd(&s_hist[(int)b], 1u);
    }
    __syncthreads();

    // --- per-thread scale for its own 4 columns ---
    const int col = (blockIdx.x & 3) * 256 + t;   // float4-column, 0..1023
    const double K = -2.302585092994045684017991454684364208;  // ln(0.1)
    float4 s;
    {
        float sv[4];
#pragma unroll
        for (int j = 0; j < 4; ++j) {
            const int c = col * 4 + j;
            double b = ((double)FEATS * (means[c] - xmin)) / denom;
            unsigned cnt = s_hist[(int)b];
            double dr = (cnt == 1u) ? 0.1 : exp(K / (0.6 * (double)cnt));
            double sg = sqrt(dr / (1.0 - dr));
            sv[j] = (float)(1.0 + sg * (double)noise[c]);
        }
        s.x = sv[0]; s.y = sv[1]; s.z = sv[2]; s.w = sv[3];
    }

    // --- streaming scale of 16 rows ---
    const int row0 = (blockIdx.x >> 2) * SROWS;
    const float4* pin = (const float4*)in + (size_t)row0 * (FEATS / 4) + col;
    float4* pout = (float4*)out + (size_t)row0 * (FEATS / 4) + col;
#pragma unroll
    for (int r = 0; r < SROWS; ++r) {
        float4 v = pin[(size_t)r * (FEATS / 4)];
        v.x *= s.x; v.y *= s.y; v.z *= s.z; v.w *= s.w;
        // nontemporal: don't let the out-stream evict the L3-resident input
        v4f nv = {v.x, v.y, v.z, v.w};
        __builtin_nontemporal_store(nv, (v4f*)&pout[(size_t)r * (FEATS / 4)]);
    }
}

extern "C" void kernel_launch(void* const* d_in, const int* in_sizes, int n_in,
                              void* d_out, int out_size, void* d_ws, size_t ws_size,
                              hipStream_t stream) {
    const float* in = (const float*)d_in[0];
    const float* noise = (const float*)d_in[1];
    float* out = (float*)d_out;
    double* partials = (double*)d_ws;
    double* means = partials + (size_t)CHUNKS * FEATS;

    dim3 g1(4, CHUNKS);
    colsum_part<<<g1, 256, 0, stream>>>(in, partials);
    reduce_mean<<<RBLK, 256, 0, stream>>>(partials, means);
    scale_fused<<<4 * (BATCH / SROWS), 256, 0, stream>>>(in, means, noise, out);
}